// Round 11
// baseline (261.820 us; speedup 1.0000x reference)
//
#include <hip/hip_runtime.h>

// Problem constants (B=2048, F=512, U=512, G=64, REG_STRENGTH=1.0)
#define B_SZ 2048
#define F_SZ 512
#define U_SZ 512
#define G_SZ 64
#define REG_STRENGTH 1.0f

// prep: histogram/prefix(shfl-scan)/scatter + workspace zeroing (proven).
// gemm: ZERO-BARRIER, WAVE-PRIVATE-LDS design.
//   wave = (group g, 16-col tile ct, 32-row half mh). 4096 waves, 1024 blocks
//   x 256 thr; each block's 4 waves are fully independent (private 8 KB LDS
//   slab each, no __syncthreads anywhere in the GEMM).
//   - X: staged to the wave's private LDS (r4-proven zero-conflict swizzle);
//     per-wave in-order DS ordering replaces barriers.
//   - W: fragment-direct from global (per-lane 32B contiguous; wave = 16
//     fully-used 128B lines/instr -- the good direct pattern, unlike r2/r3).
//   - 1-step register rotation, fully unrolled, UNCONDITIONAL assignments
//     (r5-r8,r10 lesson: conditional/asm-fenced pipeline state -> scratch).
//   Cross-round evidence: every per-K-step-barrier kernel sits at 43-63 us
//   (r4/r9) because the barrier locks all waves to the slowest load each
//   step; this removes the coupling entirely.
#define THREADS 256
#define NBLOCKS 1024        // bid&63 == g -> bid%8 == g%8 (XCD co-location)
#define NWAVES_TOT 4096
#define NSTEP 8             // stage-steps of BK=64 (2 MFMA k-slices each)

typedef float f32x4 __attribute__((ext_vector_type(4)));
typedef __bf16 bf16x8 __attribute__((ext_vector_type(8)));

#define MFMA(a, b, c) __builtin_amdgcn_mfma_f32_16x16x32_bf16((a), (b), (c), 0, 0, 0)

// fp32 -> (hi, lo) bf16 split (RNE). Dropped lo*lo matmul term is O(2^-18):
// fp32-grade accuracy (absmax 0.015625 every round since r1).
static __device__ __forceinline__ void split4(const f32x4 v, ushort4* h,
                                              ushort4* l) {
  unsigned short hb[4], lb[4];
#pragma unroll
  for (int i = 0; i < 4; ++i) {
    const __bf16 t = (__bf16)v[i];
    hb[i] = __builtin_bit_cast(unsigned short, t);
    lb[i] = __builtin_bit_cast(unsigned short, (__bf16)(v[i] - (float)t));
  }
  *h = make_ushort4(hb[0], hb[1], hb[2], hb[3]);
  *l = make_ushort4(lb[0], lb[1], lb[2], lb[3]);
}

static __device__ __forceinline__ void cvt8(const f32x4 a, const f32x4 b,
                                            bf16x8& h, bf16x8& l) {
#pragma unroll
  for (int i = 0; i < 4; ++i) {
    const __bf16 t = (__bf16)a[i];
    h[i] = t;
    l[i] = (__bf16)(a[i] - (float)t);
  }
#pragma unroll
  for (int i = 0; i < 4; ++i) {
    const __bf16 t = (__bf16)b[i];
    h[4 + i] = t;
    l[4 + i] = (__bf16)(b[i] - (float)t);
  }
}

// r4-proven LDS tile: row stride 128 B (64 bf16), XOR swizzle (row&7)<<4 --
// measured SQ_LDS_BANK_CONFLICT == 0 with the matching fragment reads.
static __device__ __forceinline__ void stage4(unsigned short* __restrict__ H,
                                              unsigned short* __restrict__ L,
                                              int row, int kq, const f32x4 v) {
  int byte = (row << 7) + (kq << 3);
  byte ^= (row & 7) << 4;
  ushort4 h, l;
  split4(v, &h, &l);
  *(ushort4*)((char*)H + byte) = h;
  *(ushort4*)((char*)L + byte) = l;
}

static __device__ __forceinline__ int fragoff(int row, int kk, int lhi) {
  int byte = (row << 7) + (kk << 6) + (lhi << 4);
  byte ^= (row & 7) << 4;
  return byte;
}

// ---------------------------------------------------------------------------
// Kernel A: histogram -> shfl scan -> scatter; zeroes wsf/done.
// ---------------------------------------------------------------------------
__global__ __launch_bounds__(1024) void prep_kernel(
    const int* __restrict__ gid, int* __restrict__ counts,
    int* __restrict__ rowstart, int* __restrict__ order,
    float* __restrict__ wsf, unsigned* __restrict__ done) {
  __shared__ int cnt_s[G_SZ];
  __shared__ int cur_s[G_SZ];
  const int tid = threadIdx.x;

  if (tid < G_SZ) cnt_s[tid] = 0;
  if (tid == 0) { wsf[0] = 0.0f; *done = 0u; }
  __syncthreads();

  for (int b = tid; b < B_SZ; b += 1024) atomicAdd(&cnt_s[gid[b]], 1);
  __syncthreads();

  if (tid < G_SZ) {  // wave 0: shfl inclusive scan -> exclusive
    const int c = cnt_s[tid];
    int inc = c;
#pragma unroll
    for (int o = 1; o < G_SZ; o <<= 1) {
      const int t = __shfl_up(inc, o, 64);
      if (tid >= o) inc += t;
    }
    counts[tid] = c;
    rowstart[tid] = inc - c;
    cur_s[tid] = inc - c;
  }
  __syncthreads();

  for (int b = tid; b < B_SZ; b += 1024) {
    int pos = atomicAdd(&cur_s[gid[b]], 1);
    order[pos] = b;
  }
}

// ---------------------------------------------------------------------------
// One 32-row chunk for one wave: barrier-free, private-LDS, fully unrolled.
// ---------------------------------------------------------------------------
template <bool DOREG>
static __device__ __forceinline__ void run_rows(
    const float* __restrict__ x, const int* __restrict__ order, int rs,
    int r0, int cnt, const float* __restrict__ wp,
    const float* __restrict__ w0p, unsigned short* __restrict__ H,
    unsigned short* __restrict__ L, int lane, int llo, int lhi,
    const float* __restrict__ b_mu, int g, int mycol,
    float* __restrict__ out, float& regp) {
  const int rowbase = lane >> 4;  // staging row base 0..3 (+4u -> 0..31)
  const int kq = lane & 15;       // staging quad within 64-float row chunk

  const float* xq[8];
#pragma unroll
  for (int u = 0; u < 8; ++u) {
    int sl = r0 + rowbase + (u << 2);
    if (sl >= cnt) sl = cnt - 1;  // dup row; never stored
    xq[u] = x + ((size_t)order[rs + sl] << 9) + (kq << 2);
  }

  f32x4 acc0 = {0.f, 0.f, 0.f, 0.f};
  f32x4 acc1 = {0.f, 0.f, 0.f, 0.f};

  // ---- prologue: load step 0 (X + W frags), stage X0 into private LDS ----
  f32x4 xr[8];
#pragma unroll
  for (int u = 0; u < 8; ++u) xr[u] = *(const f32x4*)(xq[u]);
  f32x4 wc[4];
  wc[0] = *(const f32x4*)(wp + 0);
  wc[1] = *(const f32x4*)(wp + 4);
  wc[2] = *(const f32x4*)(wp + 32);
  wc[3] = *(const f32x4*)(wp + 36);
  if (DOREG) {
    const f32x4 z0 = *(const f32x4*)(w0p + 0);
    const f32x4 z1 = *(const f32x4*)(w0p + 4);
    const f32x4 z2 = *(const f32x4*)(w0p + 32);
    const f32x4 z3 = *(const f32x4*)(w0p + 36);
#pragma unroll
    for (int i = 0; i < 4; ++i) {
      const float d0 = wc[0][i] - z0[i], d1 = wc[1][i] - z1[i];
      const float d2 = wc[2][i] - z2[i], d3 = wc[3][i] - z3[i];
      regp += d0 * d0 + d1 * d1 + d2 * d2 + d3 * d3;
    }
  }
#pragma unroll
  for (int u = 0; u < 8; ++u) stage4(H, L, rowbase + (u << 2), kq, xr[u]);

  // ---- 8 stage-steps, zero barriers, 1-step rotation (unconditional) ----
#pragma unroll
  for (int s = 0; s < NSTEP; ++s) {
    f32x4 xn[8], wn[4];
    if (s + 1 < NSTEP) {  // compile-time after unroll
      const int ko = (s + 1) << 6;
#pragma unroll
      for (int u = 0; u < 8; ++u) xn[u] = *(const f32x4*)(xq[u] + ko);
      wn[0] = *(const f32x4*)(wp + ko);
      wn[1] = *(const f32x4*)(wp + ko + 4);
      wn[2] = *(const f32x4*)(wp + ko + 32);
      wn[3] = *(const f32x4*)(wp + ko + 36);
      if (DOREG) {  // each W element visited by exactly one DOREG wave/step
        const f32x4 z0 = *(const f32x4*)(w0p + ko);
        const f32x4 z1 = *(const f32x4*)(w0p + ko + 4);
        const f32x4 z2 = *(const f32x4*)(w0p + ko + 32);
        const f32x4 z3 = *(const f32x4*)(w0p + ko + 36);
#pragma unroll
        for (int i = 0; i < 4; ++i) {
          const float d0 = wn[0][i] - z0[i], d1 = wn[1][i] - z1[i];
          const float d2 = wn[2][i] - z2[i], d3 = wn[3][i] - z3[i];
          regp += d0 * d0 + d1 * d1 + d2 * d2 + d3 * d3;
        }
      }
    }
    // compute step s: W frags from registers, X frags from private LDS
#pragma unroll
    for (int kk = 0; kk < 2; ++kk) {
      bf16x8 wh, wl;
      cvt8(wc[kk << 1], wc[(kk << 1) + 1], wh, wl);
      {
        const bf16x8 ah = *(const bf16x8*)((const char*)H + fragoff(llo, kk, lhi));
        const bf16x8 al = *(const bf16x8*)((const char*)L + fragoff(llo, kk, lhi));
        acc0 = MFMA(ah, wh, acc0);
        acc0 = MFMA(ah, wl, acc0);
        acc0 = MFMA(al, wh, acc0);
      }
      {
        const int ar = 16 + llo;
        const bf16x8 ah = *(const bf16x8*)((const char*)H + fragoff(ar, kk, lhi));
        const bf16x8 al = *(const bf16x8*)((const char*)L + fragoff(ar, kk, lhi));
        acc1 = MFMA(ah, wh, acc1);
        acc1 = MFMA(ah, wl, acc1);
        acc1 = MFMA(al, wh, acc1);
      }
    }
    // stage step s+1 (writes AFTER this step's reads; per-wave DS in-order)
    if (s + 1 < NSTEP) {
#pragma unroll
      for (int u = 0; u < 8; ++u) stage4(H, L, rowbase + (u << 2), kq, xn[u]);
#pragma unroll
      for (int q = 0; q < 4; ++q) wc[q] = wn[q];
    }
  }

  // ---- epilogue: D row = 4*lhi + j, col = llo; scatter by order ----
  const float bias = b_mu[(g << 9) + mycol];
#pragma unroll
  for (int j = 0; j < 4; ++j) {
    const int slot = r0 + (lhi << 2) + j;
    if (slot < cnt)
      out[(size_t)order[rs + slot] * U_SZ + mycol] = acc0[j] + bias;
  }
#pragma unroll
  for (int j = 0; j < 4; ++j) {
    const int slot = r0 + 16 + (lhi << 2) + j;
    if (slot < cnt)
      out[(size_t)order[rs + slot] * U_SZ + mycol] = acc1[j] + bias;
  }
}

// ---------------------------------------------------------------------------
// Kernel B: grouped GEMM, 4 independent waves per block, fused reg loss +
// finalize. No __syncthreads anywhere.
// ---------------------------------------------------------------------------
__global__ __launch_bounds__(THREADS, 1) void gemm_kernel(
    const float* __restrict__ x, const float* __restrict__ w_mu,
    const float* __restrict__ b_mu, const float* __restrict__ w0_mu,
    const float* __restrict__ b0_mu, float* __restrict__ out,
    float* __restrict__ wsf, unsigned* __restrict__ done,
    const int* __restrict__ counts, const int* __restrict__ rowstart,
    const int* __restrict__ order) {
  // wave-private slabs: [wave][hi/lo][32 rows x 64 bf16] = 4 x 8 KB = 32 KB
  __shared__ __align__(16) unsigned short XS[4][2][32 * 64];

  const int bid = blockIdx.x;
  const int g = bid & 63;   // bid%8 == g%8 -> a group's waves share an XCD
  const int cq = bid >> 6;  // 0..15

  const int tid = threadIdx.x;
  const int wv = tid >> 6;
  const int lane = tid & 63;
  const int ct = (cq << 1) | (wv >> 1);  // 16-col tile 0..31
  const int mh = wv & 1;                 // 32-row half
  const int llo = lane & 15;
  const int lhi = lane >> 4;

  unsigned short* H = &XS[wv][0][0];
  unsigned short* L = &XS[wv][1][0];

  const int cnt = counts[g];

  if (cnt > 0) {
    const int rs = rowstart[g];
    const int mycol = (ct << 4) + llo;
    const float* __restrict__ wp =
        w_mu + ((size_t)g << 18) + ((size_t)mycol << 9) + (lhi << 3);
    const float* __restrict__ w0p = w0_mu + ((size_t)mycol << 9) + (lhi << 3);

    float regp = 0.0f;
    if (bid < 64 && wv == 0) {  // ct==0 && mh==0: fused bias reg-loss
#pragma unroll
      for (int u = 0; u < 8; ++u) {
        const int idx = (u << 6) + lane;
        const float d = b_mu[(g << 9) + idx] - b0_mu[idx];
        regp += d * d;
      }
    }

    // chunk loop: mh==0 covers rows [mc,mc+32), mh==1 [mc+32,mc+64)
    for (int mc = 0; mc + (mh << 5) < cnt; mc += 64) {
      const int r0 = mc + (mh << 5);
      if (mc == 0 && mh == 0) {
        run_rows<true>(x, order, rs, r0, cnt, wp, w0p, H, L, lane, llo, lhi,
                       b_mu, g, mycol, out, regp);
      } else {
        run_rows<false>(x, order, rs, r0, cnt, wp, w0p, H, L, lane, llo, lhi,
                        b_mu, g, mycol, out, regp);
      }
    }

    // wave-level reduce (only mh==0 waves hold reg partials)
    if (mh == 0) {
#pragma unroll
      for (int o = 32; o > 0; o >>= 1) regp += __shfl_down(regp, o, 64);
      if (lane == 0) atomicAdd(wsf, (float)cnt * regp);
    }
  }

  // fused finalize: last WAVE (incl. idle ones) writes the reg-loss scalar
  if (lane == 0) {
    __threadfence();
    if (atomicAdd(done, 1u) == (unsigned)(NWAVES_TOT - 1)) {
      const float v = atomicAdd(wsf, 0.0f);  // coherent device-scope read
      out[(size_t)B_SZ * U_SZ] = REG_STRENGTH * v;
    }
  }
}

extern "C" void kernel_launch(void* const* d_in, const int* in_sizes, int n_in,
                              void* d_out, int out_size, void* d_ws,
                              size_t ws_size, hipStream_t stream) {
  (void)in_sizes; (void)n_in; (void)out_size; (void)ws_size;
  const float* x     = (const float*)d_in[0];
  const int*   gid   = (const int*)d_in[1];
  const float* w_mu  = (const float*)d_in[2];
  const float* b_mu  = (const float*)d_in[3];
  const float* w0_mu = (const float*)d_in[4];
  const float* b0_mu = (const float*)d_in[5];

  float*    wsf      = (float*)d_ws;         // [0]
  unsigned* done     = (unsigned*)d_ws + 1;  // [1]
  int*      counts   = (int*)d_ws + 2;
  int*      rowstart = (int*)d_ws + 2 + G_SZ;
  int*      order    = (int*)d_ws + 2 + 2 * G_SZ;

  prep_kernel<<<1, 1024, 0, stream>>>(gid, counts, rowstart, order, wsf, done);
  gemm_kernel<<<NBLOCKS, THREADS, 0, stream>>>(
      x, w_mu, b_mu, w0_mu, b0_mu, (float*)d_out, wsf, done,
      counts, rowstart, order);
}

// Round 12
// 136.851 us; speedup vs baseline: 1.9132x; 1.9132x over previous
//
#include <hip/hip_runtime.h>

// Problem constants (B=2048, F=512, U=512, G=64, REG_STRENGTH=1.0)
#define B_SZ 2048
#define F_SZ 512
#define U_SZ 512
#define G_SZ 64
#define REG_STRENGTH 1.0f

// CONSOLIDATION ROUND: gemm_kernel is byte-identical to the round-4 build --
// the best measured (43.5 us dispatch, VGPR 108, WRITE 4.1 MB, zero
// conflicts, zero scratch). 12 structures tried; every alternative (deeper
// pipelines, counted asm barriers, barrier-free, wave-private LDS, direct
// fragment loads) measured worse or hit the compiler's scratch-demotion
// pathology. Changes this round are OUTSIDE the gemm: workspace zeroing
// folded into prep (one fewer enqueue) and prep's serial scan -> shfl scan.
#define THREADS 256
#define NBLOCKS 512   // bid = nt*64 + g -> bid%8 = g%8: group's blocks share XCD
#define MC 64         // M rows per chunk (cnt ~ 32, <= 64 in practice)
#define BK 64         // K per step
#define NSTEP (F_SZ / BK)  // 8

typedef float f32x4 __attribute__((ext_vector_type(4)));
typedef __bf16 bf16x8 __attribute__((ext_vector_type(8)));

#define MFMA(a, b, c) __builtin_amdgcn_mfma_f32_16x16x32_bf16((a), (b), (c), 0, 0, 0)

// fp32 -> (hi, lo) bf16 split of a float4 (RNE casts -> v_cvt_pk_bf16_f32).
// Dropped lo*lo matmul term is O(2^-18): fp32-grade accuracy (verified r1-r11).
static __device__ __forceinline__ void split4(const f32x4 v, ushort4* h,
                                              ushort4* l) {
  unsigned short hb[4], lb[4];
#pragma unroll
  for (int i = 0; i < 4; ++i) {
    const __bf16 t = (__bf16)v[i];
    hb[i] = __builtin_bit_cast(unsigned short, t);
    lb[i] = __builtin_bit_cast(unsigned short, (__bf16)(v[i] - (float)t));
  }
  *h = make_ushort4(hb[0], hb[1], hb[2], hb[3]);
  *l = make_ushort4(lb[0], lb[1], lb[2], lb[3]);
}

// ---------------------------------------------------------------------------
// Kernel A: histogram -> shfl scan -> scatter; zeroes wsf/done (folds the
// former 8-byte memset dispatch).
// ---------------------------------------------------------------------------
__global__ __launch_bounds__(1024) void prep_kernel(
    const int* __restrict__ gid, int* __restrict__ counts,
    int* __restrict__ rowstart, int* __restrict__ order,
    float* __restrict__ wsf, unsigned* __restrict__ done) {
  __shared__ int cnt_s[G_SZ];
  __shared__ int cur_s[G_SZ];
  const int tid = threadIdx.x;

  if (tid < G_SZ) cnt_s[tid] = 0;
  if (tid == 0) { wsf[0] = 0.0f; *done = 0u; }
  __syncthreads();

  for (int b = tid; b < B_SZ; b += 1024) atomicAdd(&cnt_s[gid[b]], 1);
  __syncthreads();

  if (tid < G_SZ) {  // wave 0: shfl inclusive scan -> exclusive
    const int c = cnt_s[tid];
    int inc = c;
#pragma unroll
    for (int o = 1; o < G_SZ; o <<= 1) {
      const int t = __shfl_up(inc, o, 64);
      if (tid >= o) inc += t;
    }
    counts[tid] = c;
    rowstart[tid] = inc - c;
    cur_s[tid] = inc - c;
  }
  __syncthreads();

  for (int b = tid; b < B_SZ; b += 1024) {
    int pos = atomicAdd(&cur_s[gid[b]], 1);
    order[pos] = b;
  }
}

// ---------------------------------------------------------------------------
// Kernel B: grouped GEMM (LDS-staged MFMA) + fused reg loss + finalize.
// BYTE-IDENTICAL to the round-4 43.5 us build.
// ---------------------------------------------------------------------------
__global__ __launch_bounds__(THREADS, 2) void gemm_kernel(
    const float* __restrict__ x, const float* __restrict__ w_mu,
    const float* __restrict__ b_mu, const float* __restrict__ w0_mu,
    const float* __restrict__ b0_mu, float* __restrict__ out,
    float* __restrict__ wsf, unsigned* __restrict__ done,
    const int* __restrict__ counts, const int* __restrict__ rowstart,
    const int* __restrict__ order) {
  // bf16 planes, row stride 64 elems (128 B), XOR-swizzled. 4*2*8KB = 64 KB.
  __shared__ __align__(16) unsigned short WH[2][MC * BK];
  __shared__ __align__(16) unsigned short WL[2][MC * BK];
  __shared__ __align__(16) unsigned short XH[2][MC * BK];
  __shared__ __align__(16) unsigned short XL[2][MC * BK];
  __shared__ float red_s[4];

  const int bid = blockIdx.x;
  const int g = bid & 63;   // blocks of a group: bid % 8 == g % 8 -> one XCD
  const int nt = bid >> 6;  // 64-col tile 0..7
  const int n0 = nt << 6;

  const int tid = threadIdx.x;
  const int lane = tid & 63;
  const int wv = tid >> 6;    // wave -> 16-col slice
  const int llo = lane & 15;  // frag row/col within 16-tile
  const int lhi = lane >> 4;  // frag k-subchunk

  const int srow = tid >> 4;  // staging: row base 0..15 (u adds 16,32,48)
  const int kq = tid & 15;    // staging: float4 within row (coalesced)

  const int cnt = counts[g];

  if (cnt > 0) {
    const int rs = rowstart[g];
    const int mycol = n0 + (wv << 4) + llo;
    const float* __restrict__ wgp =
        w_mu + ((size_t)g << 18) + (size_t)(n0 + srow) * F_SZ + (kq << 2);
    const float* __restrict__ w0p =
        w0_mu + (size_t)(n0 + srow) * F_SZ + (kq << 2);

    float regp = 0.0f;
    if (nt == 0) {  // fused bias reg-loss, once per group
#pragma unroll
      for (int u = 0; u < 2; ++u) {
        const int idx = (u << 8) + tid;
        const float d = b_mu[(g << 9) + idx] - b0_mu[idx];
        regp += d * d;
      }
    }

    for (int mc = 0; mc < cnt; mc += MC) {  // one pass in practice (cnt<=64)
      const int rc = min(MC, cnt - mc);
      const int mts = (rc + 15) >> 4;       // active 16-row m-tiles
      const bool doreg = (mc == 0);

      const float* xp[4];
#pragma unroll
      for (int u = 0; u < 4; ++u) {
        int sl = mc + srow + (u << 4);
        if (sl >= cnt) sl = cnt - 1;  // dup row; guarded at store
        xp[u] = x + (size_t)order[rs + sl] * F_SZ + (kq << 2);
      }

      f32x4 acc[4];
#pragma unroll
      for (int m = 0; m < 4; ++m) acc[m] = (f32x4){0.f, 0.f, 0.f, 0.f};

      // ---- prologue: coalesced load + stage step 0 into buffer 0 ----
      f32x4 wr[4], xr[4];
#pragma unroll
      for (int u = 0; u < 4; ++u) wr[u] = *(const f32x4*)(wgp + (u << 13));
#pragma unroll
      for (int u = 0; u < 4; ++u) xr[u] = *(const f32x4*)(xp[u]);
      if (doreg) {  // fused W reg-loss on the staged registers
#pragma unroll
        for (int u = 0; u < 4; ++u) {
          const f32x4 z = *(const f32x4*)(w0p + (u << 13));
#pragma unroll
          for (int i = 0; i < 4; ++i) {
            const float d = wr[u][i] - z[i];
            regp += d * d;
          }
        }
      }
#pragma unroll
      for (int u = 0; u < 4; ++u) {
        const int row = srow + (u << 4);
        int byte = (row << 7) + (kq << 3);
        byte ^= (row & 7) << 4;
        ushort4 h, l;
        split4(wr[u], &h, &l);
        *(ushort4*)((char*)&WH[0][0] + byte) = h;
        *(ushort4*)((char*)&WL[0][0] + byte) = l;
        split4(xr[u], &h, &l);
        *(ushort4*)((char*)&XH[0][0] + byte) = h;
        *(ushort4*)((char*)&XL[0][0] + byte) = l;
      }
      __syncthreads();

#pragma unroll 2
      for (int s = 0; s < NSTEP; ++s) {
        const int p = s & 1;
        // (1) issue next step's coalesced loads (land during compute)
        if (s + 1 < NSTEP) {
          const int ko = (s + 1) << 6;
#pragma unroll
          for (int u = 0; u < 4; ++u)
            wr[u] = *(const f32x4*)(wgp + (u << 13) + ko);
#pragma unroll
          for (int u = 0; u < 4; ++u) xr[u] = *(const f32x4*)(xp[u] + ko);
        }
        // (2) compute on buffer p: fragments from swizzled LDS
#pragma unroll
        for (int kk = 0; kk < 2; ++kk) {
          const int wrow = (wv << 4) + llo;
          int wb = (wrow << 7) + (kk << 6) + (lhi << 4);
          wb ^= (wrow & 7) << 4;
          const bf16x8 wh = *(const bf16x8*)((const char*)&WH[p][0] + wb);
          const bf16x8 wl = *(const bf16x8*)((const char*)&WL[p][0] + wb);
#pragma unroll
          for (int m = 0; m < 4; ++m) {
            if (m < mts) {
              const int ar = (m << 4) + llo;
              int ab = (ar << 7) + (kk << 6) + (lhi << 4);
              ab ^= (ar & 7) << 4;
              const bf16x8 ah = *(const bf16x8*)((const char*)&XH[p][0] + ab);
              const bf16x8 al = *(const bf16x8*)((const char*)&XL[p][0] + ab);
              acc[m] = MFMA(ah, wh, acc[m]);
              acc[m] = MFMA(ah, wl, acc[m]);
              acc[m] = MFMA(al, wh, acc[m]);
            }
          }
        }
        // (3) reg-loss + stage prefetched regs into the other buffer
        if (s + 1 < NSTEP) {
          if (doreg) {
            const int ko = (s + 1) << 6;
#pragma unroll
            for (int u = 0; u < 4; ++u) {
              const f32x4 z = *(const f32x4*)(w0p + (u << 13) + ko);
#pragma unroll
              for (int i = 0; i < 4; ++i) {
                const float d = wr[u][i] - z[i];
                regp += d * d;
              }
            }
          }
          const int q = p ^ 1;
#pragma unroll
          for (int u = 0; u < 4; ++u) {
            const int row = srow + (u << 4);
            int byte = (row << 7) + (kq << 3);
            byte ^= (row & 7) << 4;
            ushort4 h, l;
            split4(wr[u], &h, &l);
            *(ushort4*)((char*)&WH[q][0] + byte) = h;
            *(ushort4*)((char*)&WL[q][0] + byte) = l;
            split4(xr[u], &h, &l);
            *(ushort4*)((char*)&XH[q][0] + byte) = h;
            *(ushort4*)((char*)&XL[q][0] + byte) = l;
          }
        }
        __syncthreads();
      }

      // ---- epilogue: D row = 4*lhi + j, col = llo; scatter by order ----
      const float bias = b_mu[(g << 9) + mycol];
#pragma unroll
      for (int m = 0; m < 4; ++m) {
        if (m < mts) {
#pragma unroll
          for (int j = 0; j < 4; ++j) {
            const int slot = mc + (m << 4) + (lhi << 2) + j;
            if (slot < cnt) {
              out[(size_t)order[rs + slot] * U_SZ + mycol] = acc[m][j] + bias;
            }
          }
        }
      }
    }

    // ---- block-reduce reg partials, weight by cnt, one atomic ----
#pragma unroll
    for (int o = 32; o > 0; o >>= 1) regp += __shfl_down(regp, o, 64);
    if (lane == 0) red_s[wv] = regp;
    __syncthreads();
    if (tid == 0)
      atomicAdd(wsf, (float)cnt * (red_s[0] + red_s[1] + red_s[2] + red_s[3]));
  }

  // fused finalize: last block writes the reg-loss scalar
  if (tid == 0) {
    __threadfence();
    if (atomicAdd(done, 1u) == (unsigned)(NBLOCKS - 1)) {
      const float v = atomicAdd(wsf, 0.0f);  // coherent device-scope read
      out[(size_t)B_SZ * U_SZ] = REG_STRENGTH * v;
    }
  }
}

extern "C" void kernel_launch(void* const* d_in, const int* in_sizes, int n_in,
                              void* d_out, int out_size, void* d_ws,
                              size_t ws_size, hipStream_t stream) {
  (void)in_sizes; (void)n_in; (void)out_size; (void)ws_size;
  const float* x     = (const float*)d_in[0];
  const int*   gid   = (const int*)d_in[1];
  const float* w_mu  = (const float*)d_in[2];
  const float* b_mu  = (const float*)d_in[3];
  const float* w0_mu = (const float*)d_in[4];
  const float* b0_mu = (const float*)d_in[5];

  float*    wsf      = (float*)d_ws;         // [0]
  unsigned* done     = (unsigned*)d_ws + 1;  // [1]
  int*      counts   = (int*)d_ws + 2;
  int*      rowstart = (int*)d_ws + 2 + G_SZ;
  int*      order    = (int*)d_ws + 2 + 2 * G_SZ;

  prep_kernel<<<1, 1024, 0, stream>>>(gid, counts, rowstart, order, wsf, done);
  gemm_kernel<<<NBLOCKS, THREADS, 0, stream>>>(
      x, w_mu, b_mu, w0_mu, b0_mu, (float*)d_out, wsf, done,
      counts, rowstart, order);
}